// Round 7
// baseline (378.660 us; speedup 1.0000x reference)
//
#include <hip/hip_runtime.h>

#define N_PTS 262144
#define X_STRIDE 79

using floatx4   = __attribute__((ext_vector_type(4))) float;
using floatx4a  = __attribute__((ext_vector_type(4), aligned(4))) float;
using floatx16  = __attribute__((ext_vector_type(16))) float;
using half8     = __attribute__((ext_vector_type(8))) _Float16;
using ushort8v  = __attribute__((ext_vector_type(8))) unsigned short;
using uint2v    = __attribute__((ext_vector_type(2))) unsigned int;

__device__ __forceinline__ unsigned short f2h(float f) {
  _Float16 h = (_Float16)f;
  return __builtin_bit_cast(unsigned short, h);
}
// pack 2 f32 -> 2 f16 in one VALU op (v_cvt_pkrtz_f16_f32)
__device__ __forceinline__ unsigned int pk2(float a, float b) {
  return __builtin_bit_cast(unsigned int, __builtin_amdgcn_cvt_pkrtz(a, b));
}

// ---- weight table: FRAGMENT-MAJOR fp16 -------------------------------------
// 32x32x16 layers (uw1,uw2,nw0,nw2,nw4,nw6): chunk (j,s,lane) at
//   off + ((j*KT+s)*64+lane)*8 holds W^T[j*32+(lane&31)][s*16+(lane>>5)*8+..], KT=KP/16.
// 16x16x32 layers (fw1,fw2,bw1,bw2,bw3,nw8): holds
//   W^T[j*16+(lane&15)][s*32+(lane>>4)*8+..], KT=KP/32.
// layer:        fw1 fw2 uw1 uw2 bw1 bw2 bw3 nw0 nw2 nw4 nw6 nw8
__device__ const int T_KS[12]  = {63, 64, 63,128,128, 64, 64,140,256,396,256,256};
__device__ const int T_NS[12]  = {64, 64,128, 64, 64, 64, 64,256,256,256,256, 12};
__device__ const int T_KP[12]  = {64, 64, 64,128,128, 64, 64,144,256,400,256,256};
__device__ const int T_OFF[13] = {0,4096,8192,16384,24576,32768,36864,40960,
                                  77824,143360,245760,311296,315392};
#define OFF_FW1 0
#define OFF_FW2 4096
#define OFF_UW1 8192
#define OFF_UW2 16384
#define OFF_BW1 24576
#define OFF_BW2 32768
#define OFF_BW3 36864
#define OFF_NW0 40960
#define OFF_NW2 77824
#define OFF_NW4 143360
#define OFF_NW6 245760
#define OFF_NW8 311296
#define WT_TOTAL 315392

// ---- 32x32x16 MFMA accum: D(features x points) = W^T(A) x X^T(B) -----------
template<int NJ, int NM>
__device__ __forceinline__ void accum32(floatx16 (&acc)[NJ][NM],
    const unsigned short* ldsB, int strideB, int mrow0,
    const unsigned short* wtL, int KTtot, int jg0,
    int sBegin, int sEnd, int sBBase) {
  const int lane = threadIdx.x & 63;
  const int pr = lane & 31, h = lane >> 5;
#pragma unroll 8
  for (int s = sBegin; s < sEnd; ++s) {
    half8 b[NM];
#pragma unroll
    for (int m = 0; m < NM; ++m)
      b[m] = *reinterpret_cast<const half8*>(
          ldsB + (mrow0 + m * 32 + pr) * strideB + (s - sBBase) * 16 + h * 8);
#pragma unroll
    for (int j = 0; j < NJ; ++j) {
      half8 w = *reinterpret_cast<const half8*>(
          wtL + (size_t)(((jg0 + j) * KTtot + s) * 64 + lane) * 8);
#pragma unroll
      for (int m = 0; m < NM; ++m)
        acc[j][m] = __builtin_amdgcn_mfma_f32_32x32x16_f16(w, b[m], acc[j][m], 0, 0, 0);
    }
  }
}

template<int NJ, int NM>
__device__ __forceinline__ void zero32(floatx16 (&acc)[NJ][NM]) {
#pragma unroll
  for (int j = 0; j < NJ; ++j)
#pragma unroll
    for (int m = 0; m < NM; ++m)
#pragma unroll
      for (int r = 0; r < 16; ++r) acc[j][m][r] = 0.f;
}

// 32x32 epilogue: D row=feat=(reg&3)+8*(reg>>2)+4*(lane>>5), col=pt=lane&31.
template<int NJ, int NM>
__device__ __forceinline__ void epi32(const floatx16 (&acc)[NJ][NM],
    unsigned short* ldsOut, int strideO, int colOff, int mrow0,
    const float* bias, int biasBase, bool relu) {
  const int lane = threadIdx.x & 63;
  const int pr = lane & 31, h = lane >> 5;
#pragma unroll
  for (int j = 0; j < NJ; ++j) {
#pragma unroll
    for (int g = 0; g < 4; ++g) {
      floatx4 b4 = *reinterpret_cast<const floatx4*>(bias + biasBase + j * 32 + g * 8 + h * 4);
#pragma unroll
      for (int m = 0; m < NM; ++m) {
        float v0 = acc[j][m][g * 4 + 0] + b4[0];
        float v1 = acc[j][m][g * 4 + 1] + b4[1];
        float v2 = acc[j][m][g * 4 + 2] + b4[2];
        float v3 = acc[j][m][g * 4 + 3] + b4[3];
        if (relu) {
          v0 = fmaxf(v0, 0.f); v1 = fmaxf(v1, 0.f);
          v2 = fmaxf(v2, 0.f); v3 = fmaxf(v3, 0.f);
        }
        uint2v hv; hv[0] = pk2(v0, v1); hv[1] = pk2(v2, v3);
        *reinterpret_cast<uint2v*>(
            ldsOut + (mrow0 + m * 32 + pr) * strideO + colOff + j * 32 + g * 8 + h * 4) = hv;
      }
    }
  }
}

// ---- 16x16x32 path: per-wave private chain (no barriers) -------------------
// B-frag: B[k=(lane>>4)*8+i][pt=lane&15]. D: col=pt=lane&15, row=feat=(lane>>4)*4+reg.
template<int NJ, int KT>
__device__ __forceinline__ void accum16nj(floatx4 (&acc)[NJ],
    const unsigned short* ldsB, int strideB, int mrow0,
    const unsigned short* wtL) {
  const int lane = threadIdx.x & 63;
  const int nh = lane & 15, q = lane >> 4;
#pragma unroll
  for (int s = 0; s < KT; ++s) {
    half8 b = *reinterpret_cast<const half8*>(
        ldsB + (mrow0 + nh) * strideB + s * 32 + q * 8);
#pragma unroll
    for (int j = 0; j < NJ; ++j) {
      half8 w = *reinterpret_cast<const half8*>(
          wtL + (size_t)((j * KT + s) * 64 + lane) * 8);
      acc[j] = __builtin_amdgcn_mfma_f32_16x16x32_f16(w, b, acc[j], 0, 0, 0);
    }
  }
}

template<int NJ>
__device__ __forceinline__ void epi16nj(const floatx4 (&acc)[NJ],
    unsigned short* ldsOut, int strideO, int colOff, int mrow0,
    const float* bias, bool relu) {
  const int lane = threadIdx.x & 63;
  const int nh = lane & 15, q = lane >> 4;
#pragma unroll
  for (int j = 0; j < NJ; ++j) {
    floatx4 b4 = *reinterpret_cast<const floatx4*>(bias + j * 16 + q * 4);
    float v0 = acc[j][0] + b4[0];
    float v1 = acc[j][1] + b4[1];
    float v2 = acc[j][2] + b4[2];
    float v3 = acc[j][3] + b4[3];
    if (relu) {
      v0 = fmaxf(v0, 0.f); v1 = fmaxf(v1, 0.f);
      v2 = fmaxf(v2, 0.f); v3 = fmaxf(v3, 0.f);
    }
    uint2v hv; hv[0] = pk2(v0, v1); hv[1] = pk2(v2, v3);
    *reinterpret_cast<uint2v*>(
        ldsOut + (mrow0 + nh) * strideO + colOff + j * 16 + q * 4) = hv;
  }
}

// ---- kernel 1: weight repack + scalar output -------------------------------
struct PrepArgs { const float* src[12]; };

__global__ __launch_bounds__(256) void prep_k(PrepArgs a, unsigned short* wt,
                                              float* outM, float Mval) {
  int chunk = blockIdx.x * 256 + threadIdx.x;  // one thread per 8-half chunk
  if (chunk == 0) *outM = Mval;
  if (chunk >= WT_TOTAL / 8) return;
  int gid = chunk * 8;
  int L = 0;
  while (gid >= T_OFF[L + 1]) ++L;
  int local = chunk - T_OFF[L] / 8;
  int lane = local & 63;
  int t = local >> 6;
  bool is16 = (L < 2) || (L >= 4 && L <= 6) || (L == 11);
  int n, k0;
  if (is16) {
    int KT = T_KP[L] >> 5;
    int s = t % KT, j = t / KT;
    n = j * 16 + (lane & 15);
    k0 = s * 32 + (lane >> 4) * 8;
  } else {
    int KT = T_KP[L] >> 4;
    int s = t % KT, j = t / KT;
    n = j * 32 + (lane & 31);
    k0 = s * 16 + (lane >> 5) * 8;
  }
  const float* src = a.src[L];
  int K = T_KS[L], Nn = T_NS[L];
  ushort8v o;
#pragma unroll
  for (int i = 0; i < 8; ++i) {
    int k = k0 + i;
    float v = (k < K && n < Nn) ? src[(size_t)k * Nn + n] : 0.f;
    o[i] = f2h(v);
  }
  *reinterpret_cast<ushort8v*>(wt + gid) = o;
}

// ---- kernel 2: voxel branch, 64 voxels/block -------------------------------
__global__ __launch_bounds__(256, 3) void voxel_k(const float* __restrict__ x,
                                                  const int* __restrict__ inds,
                                                  const unsigned short* __restrict__ wt,
                                                  const float* __restrict__ ub1,
                                                  const float* __restrict__ ub2,
                                                  unsigned short* __restrict__ vout, int M) {
  __shared__ unsigned short bufV[64 * 72];
  __shared__ unsigned short bufU[64 * 136];
  const int wave = threadIdx.x >> 6, lane = threadIdx.x & 63;
  const int pr = lane & 31, h = lane >> 5;
  const int v0 = blockIdx.x * 64;

  // gather: 16 float4 groups per voxel row (cols 0..63, col 63 zeroed)
  for (int idx = threadIdx.x; idx < 64 * 16; idx += 256) {
    int p = idx >> 4, g = idx & 15;
    int v = v0 + p;
    uint2v hv; hv[0] = 0u; hv[1] = 0u;
    if (v < M) {
      floatx4a f = *reinterpret_cast<const floatx4a*>(
          x + (size_t)inds[v] * X_STRIDE + g * 4);
      if (g == 15) f[3] = 0.f;  // col 63 is padding (K=63)
      hv[0] = pk2(f[0], f[1]); hv[1] = pk2(f[2], f[3]);
    }
    *reinterpret_cast<uint2v*>(bufV + p * 72 + g * 4) = hv;
  }
  __syncthreads();

  // uw1: 63->128 relu
  {
    floatx16 acc[2][1];
    zero32<2, 1>(acc);
    int jg0 = (wave & 1) * 2, m0 = (wave >> 1) * 32;
    accum32<2, 1>(acc, bufV, 72, m0, wt + OFF_UW1, 4, jg0, 0, 4, 0);
    epi32<2, 1>(acc, bufU, 136, jg0 * 32, m0, ub1, jg0 * 32, true);
  }
  __syncthreads();

  // uw2: 128->64, direct global store (pkrtz-packed b64)
  {
    floatx16 acc[1][1];
    zero32<1, 1>(acc);
    int j = wave & 1, m0 = (wave >> 1) * 32;
    accum32<1, 1>(acc, bufU, 136, m0, wt + OFF_UW2, 8, j, 0, 8, 0);
    int v = v0 + m0 + pr;
    if (v < M) {
#pragma unroll
      for (int g = 0; g < 4; ++g) {
        floatx4 b4 = *reinterpret_cast<const floatx4*>(ub2 + j * 32 + g * 8 + h * 4);
        uint2v hv;
        hv[0] = pk2(acc[0][0][g * 4 + 0] + b4[0], acc[0][0][g * 4 + 1] + b4[1]);
        hv[1] = pk2(acc[0][0][g * 4 + 2] + b4[2], acc[0][0][g * 4 + 3] + b4[3]);
        *reinterpret_cast<uint2v*>(vout + (size_t)v * 64 + j * 32 + g * 8 + h * 4) = hv;
      }
    }
  }
}

// ---- kernel 3: fused per-point pipeline, 64 pts/block ----------------------
// LDS rows = points. bufX[64][144]: x [0,76) | back [76,140) | zero [140,144).
// reg2[64][264]: front [0,64) / pcd [64,128) / t1 [128,192) / t2 [192,256)
// Front/back chain (fw1..bw3): per-wave 16-pt ownership, 16x16x32, NO barriers.
struct MainArgs {
  const float* x;
  const int* invmap;
  const unsigned short* wt;
  const unsigned short* vout;
  float* out;
  const float* fb1; const float* fb2;
  const float* bb1; const float* bb2; const float* bb3;
  const float* nb0; const float* nb2; const float* nb4; const float* nb6; const float* nb8;
};

__global__ __launch_bounds__(256, 3) void main_k(MainArgs a) {
  __shared__ unsigned short bufX[64 * 144];
  __shared__ unsigned short reg2[64 * 264];
  const int wave = threadIdx.x >> 6, lane = threadIdx.x & 63;
  const int p0 = blockIdx.x * 64;
  const int w16 = wave * 16;

  // stage x[:, :76): 19 float4 groups/row, pkrtz-packed b64 LDS writes
  for (int idx = threadIdx.x; idx < 64 * 19; idx += 256) {
    int p = idx / 19, g = idx - p * 19;
    floatx4a f = *reinterpret_cast<const floatx4a*>(
        a.x + (size_t)(p0 + p) * X_STRIDE + g * 4);
    uint2v hv; hv[0] = pk2(f[0], f[1]); hv[1] = pk2(f[2], f[3]);
    *reinterpret_cast<uint2v*>(bufX + p * 144 + g * 4) = hv;
  }
  // zero bufX cols [140,144)
  for (int idx = threadIdx.x; idx < 64; idx += 256) {
    uint2v z; z[0] = 0u; z[1] = 0u;
    *reinterpret_cast<uint2v*>(bufX + idx * 144 + 140) = z;
  }
  // gather pcd -> reg2 cols [64,128)
  for (int idx = threadIdx.x; idx < 64 * 8; idx += 256) {
    int p = idx >> 3, c = (idx & 7) * 8;
    int r = a.invmap[p0 + p];
    *reinterpret_cast<ushort8v*>(reg2 + p * 264 + 64 + c) =
        *reinterpret_cast<const ushort8v*>(a.vout + (size_t)r * 64 + c);
  }
  __syncthreads();

  // ---- front/back chain: wave-private 16 points, zero barriers ----
  {
    floatx4 acc[4];
    // fw1: pe(64) -> 64 relu -> t1
#pragma unroll
    for (int j = 0; j < 4; ++j) acc[j] = floatx4{0.f, 0.f, 0.f, 0.f};
    accum16nj<4, 2>(acc, bufX, 144, w16, a.wt + OFF_FW1);
    epi16nj<4>(acc, reg2, 264, 128, w16, a.fb1, true);
    // fw2: t1 -> front [0,64)
#pragma unroll
    for (int j = 0; j < 4; ++j) acc[j] = floatx4{0.f, 0.f, 0.f, 0.f};
    accum16nj<4, 2>(acc, reg2 + 128, 264, w16, a.wt + OFF_FW2);
    epi16nj<4>(acc, reg2, 264, 0, w16, a.fb2, false);
    // bw1: [front|pcd](128) -> 64 relu -> t1
#pragma unroll
    for (int j = 0; j < 4; ++j) acc[j] = floatx4{0.f, 0.f, 0.f, 0.f};
    accum16nj<4, 4>(acc, reg2, 264, w16, a.wt + OFF_BW1);
    epi16nj<4>(acc, reg2, 264, 128, w16, a.bb1, true);
    // bw2: t1 -> 64 relu -> t2
#pragma unroll
    for (int j = 0; j < 4; ++j) acc[j] = floatx4{0.f, 0.f, 0.f, 0.f};
    accum16nj<4, 2>(acc, reg2 + 128, 264, w16, a.wt + OFF_BW2);
    epi16nj<4>(acc, reg2, 264, 192, w16, a.bb2, true);
    // bw3: t2 -> back -> bufX cols [76,140)
#pragma unroll
    for (int j = 0; j < 4; ++j) acc[j] = floatx4{0.f, 0.f, 0.f, 0.f};
    accum16nj<4, 2>(acc, reg2 + 192, 264, w16, a.wt + OFF_BW3);
    epi16nj<4>(acc, bufX, 144, 76, w16, a.bb3, false);
  }
  __syncthreads();

  // ---- 256-wide layers: each wave NJ=2 (64 feats), NM=2 (all 64 pts) ----
  // n0: xx(144) -> 256 relu -> reg2[0:256)
  {
    floatx16 acc[2][2];
    zero32<2, 2>(acc);
    accum32<2, 2>(acc, bufX, 144, 0, a.wt + OFF_NW0, 9, wave * 2, 0, 9, 0);
    epi32<2, 2>(acc, reg2, 264, wave * 64, 0, a.nb0, wave * 64, true);
  }
  __syncthreads();
  // n2: 256 -> 256 relu, in-place
  {
    floatx16 acc[2][2];
    zero32<2, 2>(acc);
    accum32<2, 2>(acc, reg2, 264, 0, a.wt + OFF_NW2, 16, wave * 2, 0, 16, 0);
    __syncthreads();
    epi32<2, 2>(acc, reg2, 264, wave * 64, 0, a.nb2, wave * 64, true);
  }
  __syncthreads();
  // n4: [h(256)|xx(144)] -> 256 relu, in-place
  {
    floatx16 acc[2][2];
    zero32<2, 2>(acc);
    accum32<2, 2>(acc, reg2, 264, 0, a.wt + OFF_NW4, 25, wave * 2, 0, 16, 0);
    accum32<2, 2>(acc, bufX, 144, 0, a.wt + OFF_NW4, 25, wave * 2, 16, 25, 16);
    __syncthreads();
    epi32<2, 2>(acc, reg2, 264, wave * 64, 0, a.nb4, wave * 64, true);
  }
  __syncthreads();
  // n6: 256 -> 256 relu, in-place
  {
    floatx16 acc[2][2];
    zero32<2, 2>(acc);
    accum32<2, 2>(acc, reg2, 264, 0, a.wt + OFF_NW6, 16, wave * 2, 0, 16, 0);
    __syncthreads();
    epi32<2, 2>(acc, reg2, 264, wave * 64, 0, a.nb6, wave * 64, true);
  }
  __syncthreads();
  // n8: 256 -> 12 via 16x16x32; wave -> its 16 pts; direct global store
  {
    const int nh = lane & 15, q = lane >> 4;
    floatx4 acc[1];
    acc[0] = floatx4{0.f, 0.f, 0.f, 0.f};
    accum16nj<1, 8>(acc, reg2, 264, w16, a.wt + OFF_NW8);
    if (q < 3) {
      floatx4 o;
#pragma unroll
      for (int r = 0; r < 4; ++r) o[r] = acc[0][r] + a.nb8[q * 4 + r];
      *reinterpret_cast<floatx4*>(a.out + (size_t)(p0 + w16 + nh) * 12 + q * 4) = o;
    }
  }
}

// ---- launch ----------------------------------------------------------------
extern "C" void kernel_launch(void* const* d_in, const int* in_sizes, int n_in,
                              void* d_out, int out_size, void* d_ws, size_t ws_size,
                              hipStream_t stream) {
  const float* x      = (const float*)d_in[0];
  const int*   inds   = (const int*)d_in[1];
  const int*   invmap = (const int*)d_in[2];
  const int M = in_sizes[1];

  unsigned short* wt   = (unsigned short*)d_ws;                       // 631 KB
  unsigned short* vout = (unsigned short*)((char*)d_ws + (1 << 20));  // M*64*2

  PrepArgs pa;
  pa.src[0]  = (const float*)d_in[3];   // fw1
  pa.src[1]  = (const float*)d_in[5];   // fw2
  pa.src[2]  = (const float*)d_in[7];   // uw1
  pa.src[3]  = (const float*)d_in[9];   // uw2
  pa.src[4]  = (const float*)d_in[11];  // bw1
  pa.src[5]  = (const float*)d_in[13];  // bw2
  pa.src[6]  = (const float*)d_in[15];  // bw3
  pa.src[7]  = (const float*)d_in[17];  // nw0
  pa.src[8]  = (const float*)d_in[19];  // nw2
  pa.src[9]  = (const float*)d_in[21];  // nw4
  pa.src[10] = (const float*)d_in[23];  // nw6
  pa.src[11] = (const float*)d_in[25];  // nw8

  float* outM = (float*)d_out + (size_t)N_PTS * 12;
  prep_k<<<(WT_TOTAL / 8 + 255) / 256, 256, 0, stream>>>(pa, wt, outM, (float)M);

  voxel_k<<<(M + 63) / 64, 256, 0, stream>>>(x, inds, wt,
                                             (const float*)d_in[8],   // ub1
                                             (const float*)d_in[10],  // ub2
                                             vout, M);

  MainArgs ma;
  ma.x = x; ma.invmap = invmap; ma.wt = wt; ma.vout = vout; ma.out = (float*)d_out;
  ma.fb1 = (const float*)d_in[4];  ma.fb2 = (const float*)d_in[6];
  ma.bb1 = (const float*)d_in[12]; ma.bb2 = (const float*)d_in[14]; ma.bb3 = (const float*)d_in[16];
  ma.nb0 = (const float*)d_in[18]; ma.nb2 = (const float*)d_in[20];
  ma.nb4 = (const float*)d_in[22]; ma.nb6 = (const float*)d_in[24]; ma.nb8 = (const float*)d_in[26];
  main_k<<<N_PTS / 64, 256, 0, stream>>>(ma);
}

// Round 8
// 376.561 us; speedup vs baseline: 1.0056x; 1.0056x over previous
//
#include <hip/hip_runtime.h>

#define N_PTS 262144
#define X_STRIDE 79

using floatx4   = __attribute__((ext_vector_type(4))) float;
using floatx4a  = __attribute__((ext_vector_type(4), aligned(4))) float;
using floatx16  = __attribute__((ext_vector_type(16))) float;
using half8     = __attribute__((ext_vector_type(8))) _Float16;
using ushort8v  = __attribute__((ext_vector_type(8))) unsigned short;
using uint2v    = __attribute__((ext_vector_type(2))) unsigned int;

__device__ __forceinline__ unsigned short f2h(float f) {
  _Float16 h = (_Float16)f;
  return __builtin_bit_cast(unsigned short, h);
}
__device__ __forceinline__ unsigned int pk2(float a, float b) {
  return __builtin_bit_cast(unsigned int, __builtin_amdgcn_cvt_pkrtz(a, b));
}
// XOR swizzle for reg2: 256-elem rows, 16B chunks rotated by row.
__device__ __forceinline__ int swz(int row, int col) {
  return row * 256 + (((col >> 3) ^ (row & 31)) << 3) + (col & 7);
}

// ---- weight table: FRAGMENT-MAJOR fp16 (see round-7 notes) -----------------
// layer:        fw1 fw2 uw1 uw2 bw1 bw2 bw3 nw0 nw2 nw4 nw6 nw8
__device__ const int T_KS[12]  = {63, 64, 63,128,128, 64, 64,140,256,396,256,256};
__device__ const int T_NS[12]  = {64, 64,128, 64, 64, 64, 64,256,256,256,256, 12};
__device__ const int T_KP[12]  = {64, 64, 64,128,128, 64, 64,144,256,400,256,256};
__device__ const int T_OFF[13] = {0,4096,8192,16384,24576,32768,36864,40960,
                                  77824,143360,245760,311296,315392};
#define OFF_FW1 0
#define OFF_FW2 4096
#define OFF_UW1 8192
#define OFF_UW2 16384
#define OFF_BW1 24576
#define OFF_BW2 32768
#define OFF_BW3 36864
#define OFF_NW0 40960
#define OFF_NW2 77824
#define OFF_NW4 143360
#define OFF_NW6 245760
#define OFF_NW8 311296
#define WT_TOTAL 315392

template<int NJ, int NM, int SWZ>
__device__ __forceinline__ void accum32(floatx16 (&acc)[NJ][NM],
    const unsigned short* ldsB, int strideB, int mrow0, int colB,
    const unsigned short* wtL, int KTtot, int jg0,
    int sBegin, int sEnd, int sBBase) {
  const int lane = threadIdx.x & 63;
  const int pr = lane & 31, h = lane >> 5;
#pragma unroll 4
  for (int s = sBegin; s < sEnd; ++s) {
    half8 b[NM];
#pragma unroll
    for (int m = 0; m < NM; ++m) {
      int row = mrow0 + m * 32 + pr;
      int col = colB + (s - sBBase) * 16 + h * 8;
      int off = SWZ ? swz(row, col) : (row * strideB + col);
      b[m] = *reinterpret_cast<const half8*>(ldsB + off);
    }
#pragma unroll
    for (int j = 0; j < NJ; ++j) {
      half8 w = *reinterpret_cast<const half8*>(
          wtL + (size_t)(((jg0 + j) * KTtot + s) * 64 + lane) * 8);
#pragma unroll
      for (int m = 0; m < NM; ++m)
        acc[j][m] = __builtin_amdgcn_mfma_f32_32x32x16_f16(w, b[m], acc[j][m], 0, 0, 0);
    }
  }
}

template<int NJ, int NM>
__device__ __forceinline__ void zero32(floatx16 (&acc)[NJ][NM]) {
#pragma unroll
  for (int j = 0; j < NJ; ++j)
#pragma unroll
    for (int m = 0; m < NM; ++m)
#pragma unroll
      for (int r = 0; r < 16; ++r) acc[j][m][r] = 0.f;
}

template<int NJ, int NM, int SWZ>
__device__ __forceinline__ void epi32(const floatx16 (&acc)[NJ][NM],
    unsigned short* ldsOut, int strideO, int colOff, int mrow0,
    const float* bias, int biasBase, bool relu) {
  const int lane = threadIdx.x & 63;
  const int pr = lane & 31, h = lane >> 5;
#pragma unroll
  for (int j = 0; j < NJ; ++j) {
#pragma unroll
    for (int g = 0; g < 4; ++g) {
      floatx4 b4 = *reinterpret_cast<const floatx4*>(bias + biasBase + j * 32 + g * 8 + h * 4);
#pragma unroll
      for (int m = 0; m < NM; ++m) {
        float v0 = acc[j][m][g * 4 + 0] + b4[0];
        float v1 = acc[j][m][g * 4 + 1] + b4[1];
        float v2 = acc[j][m][g * 4 + 2] + b4[2];
        float v3 = acc[j][m][g * 4 + 3] + b4[3];
        if (relu) {
          v0 = fmaxf(v0, 0.f); v1 = fmaxf(v1, 0.f);
          v2 = fmaxf(v2, 0.f); v3 = fmaxf(v3, 0.f);
        }
        uint2v hv; hv[0] = pk2(v0, v1); hv[1] = pk2(v2, v3);
        int row = mrow0 + m * 32 + pr;
        int col = colOff + j * 32 + g * 8 + h * 4;
        int off = SWZ ? swz(row, col) : (row * strideO + col);
        *reinterpret_cast<uint2v*>(ldsOut + off) = hv;
      }
    }
  }
}

template<int NJ, int KT, int SWZ>
__device__ __forceinline__ void accum16nj(floatx4 (&acc)[NJ],
    const unsigned short* ldsB, int strideB, int mrow0, int colB,
    const unsigned short* wtL, int jg0) {
  const int lane = threadIdx.x & 63;
  const int nh = lane & 15, q = lane >> 4;
#pragma unroll
  for (int s = 0; s < KT; ++s) {
    int row = mrow0 + nh;
    int col = colB + s * 32 + q * 8;
    int off = SWZ ? swz(row, col) : (row * strideB + col);
    half8 b = *reinterpret_cast<const half8*>(ldsB + off);
#pragma unroll
    for (int j = 0; j < NJ; ++j) {
      half8 w = *reinterpret_cast<const half8*>(
          wtL + (size_t)(((jg0 + j) * KT + s) * 64 + lane) * 8);
      acc[j] = __builtin_amdgcn_mfma_f32_16x16x32_f16(w, b, acc[j], 0, 0, 0);
    }
  }
}

template<int NJ, int SWZ>
__device__ __forceinline__ void epi16nj(const floatx4 (&acc)[NJ],
    unsigned short* ldsOut, int strideO, int colOff, int mrow0,
    const float* bias, int biasBase, bool relu) {
  const int lane = threadIdx.x & 63;
  const int nh = lane & 15, q = lane >> 4;
#pragma unroll
  for (int j = 0; j < NJ; ++j) {
    floatx4 b4 = *reinterpret_cast<const floatx4*>(bias + biasBase + j * 16 + q * 4);
    float v0 = acc[j][0] + b4[0];
    float v1 = acc[j][1] + b4[1];
    float v2 = acc[j][2] + b4[2];
    float v3 = acc[j][3] + b4[3];
    if (relu) {
      v0 = fmaxf(v0, 0.f); v1 = fmaxf(v1, 0.f);
      v2 = fmaxf(v2, 0.f); v3 = fmaxf(v3, 0.f);
    }
    uint2v hv; hv[0] = pk2(v0, v1); hv[1] = pk2(v2, v3);
    int row = mrow0 + nh;
    int col = colOff + j * 16 + q * 4;
    int off = SWZ ? swz(row, col) : (row * strideO + col);
    *reinterpret_cast<uint2v*>(ldsOut + off) = hv;
  }
}

// ---- kernel 1: weight repack + scalar output -------------------------------
struct PrepArgs { const float* src[12]; };

__global__ __launch_bounds__(256) void prep_k(PrepArgs a, unsigned short* wt,
                                              float* outM, float Mval) {
  int chunk = blockIdx.x * 256 + threadIdx.x;
  if (chunk == 0) *outM = Mval;
  if (chunk >= WT_TOTAL / 8) return;
  int gid = chunk * 8;
  int L = 0;
  while (gid >= T_OFF[L + 1]) ++L;
  int local = chunk - T_OFF[L] / 8;
  int lane = local & 63;
  int t = local >> 6;
  bool is16 = (L < 2) || (L >= 4 && L <= 6) || (L == 11);
  int n, k0;
  if (is16) {
    int KT = T_KP[L] >> 5;
    int s = t % KT, j = t / KT;
    n = j * 16 + (lane & 15);
    k0 = s * 32 + (lane >> 4) * 8;
  } else {
    int KT = T_KP[L] >> 4;
    int s = t % KT, j = t / KT;
    n = j * 32 + (lane & 31);
    k0 = s * 16 + (lane >> 5) * 8;
  }
  const float* src = a.src[L];
  int K = T_KS[L], Nn = T_NS[L];
  ushort8v o;
#pragma unroll
  for (int i = 0; i < 8; ++i) {
    int k = k0 + i;
    float v = (k < K && n < Nn) ? src[(size_t)k * Nn + n] : 0.f;
    o[i] = f2h(v);
  }
  *reinterpret_cast<ushort8v*>(wt + gid) = o;
}

// ---- kernel 2: voxel branch (round-6 structure) ----------------------------
__global__ __launch_bounds__(256, 3) void voxel_k(const float* __restrict__ x,
                                                  const int* __restrict__ inds,
                                                  const unsigned short* __restrict__ wt,
                                                  const float* __restrict__ ub1,
                                                  const float* __restrict__ ub2,
                                                  unsigned short* __restrict__ vout, int M) {
  __shared__ unsigned short bufV[64 * 72];
  __shared__ unsigned short bufU[64 * 136];
  const int wave = threadIdx.x >> 6, lane = threadIdx.x & 63;
  const int pr = lane & 31, h = lane >> 5;
  const int v0 = blockIdx.x * 64;

  for (int idx = threadIdx.x; idx < 64 * 16; idx += 256) {
    int p = idx >> 4, g = idx & 15;
    int v = v0 + p;
    uint2v hv; hv[0] = 0u; hv[1] = 0u;
    if (v < M) {
      floatx4a f = *reinterpret_cast<const floatx4a*>(
          x + (size_t)inds[v] * X_STRIDE + g * 4);
      if (g == 15) f[3] = 0.f;
      hv[0] = pk2(f[0], f[1]); hv[1] = pk2(f[2], f[3]);
    }
    *reinterpret_cast<uint2v*>(bufV + p * 72 + g * 4) = hv;
  }
  __syncthreads();

  {
    floatx16 acc[2][1];
    zero32<2, 1>(acc);
    int jg0 = (wave & 1) * 2, m0 = (wave >> 1) * 32;
    accum32<2, 1, 0>(acc, bufV, 72, m0, 0, wt + OFF_UW1, 4, jg0, 0, 4, 0);
    epi32<2, 1, 0>(acc, bufU, 136, jg0 * 32, m0, ub1, jg0 * 32, true);
  }
  __syncthreads();

  {
    floatx16 acc[1][1];
    zero32<1, 1>(acc);
    int j = wave & 1, m0 = (wave >> 1) * 32;
    accum32<1, 1, 0>(acc, bufU, 136, m0, 0, wt + OFF_UW2, 8, j, 0, 8, 0);
    int v = v0 + m0 + pr;
    if (v < M) {
#pragma unroll
      for (int g = 0; g < 4; ++g) {
        floatx4 b4 = *reinterpret_cast<const floatx4*>(ub2 + j * 32 + g * 8 + h * 4);
        uint2v hv;
        hv[0] = pk2(acc[0][0][g * 4 + 0] + b4[0], acc[0][0][g * 4 + 1] + b4[1]);
        hv[1] = pk2(acc[0][0][g * 4 + 2] + b4[2], acc[0][0][g * 4 + 3] + b4[3]);
        *reinterpret_cast<uint2v*>(vout + (size_t)v * 64 + j * 32 + g * 8 + h * 4) = hv;
      }
    }
  }
}

// ---- kernel 3: fused pipeline, 64 pts/block, 8 waves, swizzled reg2 --------
struct MainArgs {
  const float* x;
  const int* invmap;
  const unsigned short* wt;
  const unsigned short* vout;
  float* out;
  const float* fb1; const float* fb2;
  const float* bb1; const float* bb2; const float* bb3;
  const float* nb0; const float* nb2; const float* nb4; const float* nb6; const float* nb8;
};

__global__ __launch_bounds__(512, 6) void main_k(MainArgs a) {
  __shared__ unsigned short bufX[64 * 152];   // linear: x[0,76)|back[76,140)|0
  __shared__ unsigned short reg2[64 * 256];   // swizzled
  const int wave = threadIdx.x >> 6, lane = threadIdx.x & 63;
  const int p0 = blockIdx.x * 64;

  for (int idx = threadIdx.x; idx < 64 * 19; idx += 512) {
    int p = idx / 19, g = idx - p * 19;
    floatx4a f = *reinterpret_cast<const floatx4a*>(
        a.x + (size_t)(p0 + p) * X_STRIDE + g * 4);
    uint2v hv; hv[0] = pk2(f[0], f[1]); hv[1] = pk2(f[2], f[3]);
    *reinterpret_cast<uint2v*>(bufX + p * 152 + g * 4) = hv;
  }
  for (int idx = threadIdx.x; idx < 64 * 3; idx += 512) {
    int p = idx / 3, c = (idx - p * 3) * 4;
    uint2v z; z[0] = 0u; z[1] = 0u;
    *reinterpret_cast<uint2v*>(bufX + p * 152 + 140 + c) = z;
  }
  {
    int p = threadIdx.x >> 3, cc = threadIdx.x & 7;
    int r = a.invmap[p0 + p];
    *reinterpret_cast<ushort8v*>(reg2 + p * 256 + (((8 + cc) ^ (p & 31)) << 3)) =
        *reinterpret_cast<const ushort8v*>(a.vout + (size_t)r * 64 + cc * 8);
  }
  __syncthreads();

  // ---- chain: 16x16x32, all 8 waves (m16 = 16 pts, jg2 = 2 j-tiles) ----
  const int m16 = (wave >> 1) * 16;
  const int jg2 = (wave & 1) * 2;
  {
    floatx4 acc[2];
    acc[0] = floatx4{0.f,0.f,0.f,0.f}; acc[1] = floatx4{0.f,0.f,0.f,0.f};
    accum16nj<2, 2, 0>(acc, bufX, 152, m16, 0, a.wt + OFF_FW1, jg2);
    epi16nj<2, 1>(acc, reg2, 0, 128 + jg2 * 16, m16, a.fb1, jg2 * 16, true);
    __syncthreads();
    acc[0] = floatx4{0.f,0.f,0.f,0.f}; acc[1] = floatx4{0.f,0.f,0.f,0.f};
    accum16nj<2, 2, 1>(acc, reg2, 0, m16, 128, a.wt + OFF_FW2, jg2);
    epi16nj<2, 1>(acc, reg2, 0, 0 + jg2 * 16, m16, a.fb2, jg2 * 16, false);
    __syncthreads();
    acc[0] = floatx4{0.f,0.f,0.f,0.f}; acc[1] = floatx4{0.f,0.f,0.f,0.f};
    accum16nj<2, 4, 1>(acc, reg2, 0, m16, 0, a.wt + OFF_BW1, jg2);
    epi16nj<2, 1>(acc, reg2, 0, 128 + jg2 * 16, m16, a.bb1, jg2 * 16, true);
    __syncthreads();
    acc[0] = floatx4{0.f,0.f,0.f,0.f}; acc[1] = floatx4{0.f,0.f,0.f,0.f};
    accum16nj<2, 2, 1>(acc, reg2, 0, m16, 128, a.wt + OFF_BW2, jg2);
    epi16nj<2, 1>(acc, reg2, 0, 192 + jg2 * 16, m16, a.bb2, jg2 * 16, true);
    __syncthreads();
    acc[0] = floatx4{0.f,0.f,0.f,0.f}; acc[1] = floatx4{0.f,0.f,0.f,0.f};
    accum16nj<2, 2, 1>(acc, reg2, 0, m16, 192, a.wt + OFF_BW3, jg2);
    epi16nj<2, 0>(acc, bufX, 152, 76 + jg2 * 16, m16, a.bb3, jg2 * 16, false);
    __syncthreads();
  }

  // ---- 256-wide layers: NJ=1 (32 feats/wave), NM=2 (64 pts) ----
  {
    floatx16 acc[1][2];
    zero32<1, 2>(acc);
    accum32<1, 2, 0>(acc, bufX, 152, 0, 0, a.wt + OFF_NW0, 9, wave, 0, 9, 0);
    epi32<1, 2, 1>(acc, reg2, 0, wave * 32, 0, a.nb0, wave * 32, true);
  }
  __syncthreads();
  {
    floatx16 acc[1][2];
    zero32<1, 2>(acc);
    accum32<1, 2, 1>(acc, reg2, 0, 0, 0, a.wt + OFF_NW2, 16, wave, 0, 16, 0);
    __syncthreads();
    epi32<1, 2, 1>(acc, reg2, 0, wave * 32, 0, a.nb2, wave * 32, true);
  }
  __syncthreads();
  {
    floatx16 acc[1][2];
    zero32<1, 2>(acc);
    accum32<1, 2, 1>(acc, reg2, 0, 0, 0, a.wt + OFF_NW4, 25, wave, 0, 16, 0);
    accum32<1, 2, 0>(acc, bufX, 152, 0, 0, a.wt + OFF_NW4, 25, wave, 16, 25, 16);
    __syncthreads();
    epi32<1, 2, 1>(acc, reg2, 0, wave * 32, 0, a.nb4, wave * 32, true);
  }
  __syncthreads();
  {
    floatx16 acc[1][2];
    zero32<1, 2>(acc);
    accum32<1, 2, 1>(acc, reg2, 0, 0, 0, a.wt + OFF_NW6, 16, wave, 0, 16, 0);
    __syncthreads();
    epi32<1, 2, 1>(acc, reg2, 0, wave * 32, 0, a.nb6, wave * 32, true);
  }
  __syncthreads();
  if (wave < 4) {
    const int nh = lane & 15, q = lane >> 4;
    floatx4 acc[1];
    acc[0] = floatx4{0.f, 0.f, 0.f, 0.f};
    accum16nj<1, 8, 1>(acc, reg2, 0, wave * 16, 0, a.wt + OFF_NW8, 0);
    if (q < 3) {
      floatx4 o;
#pragma unroll
      for (int r = 0; r < 4; ++r) o[r] = acc[0][r] + a.nb8[q * 4 + r];
      *reinterpret_cast<floatx4*>(a.out + (size_t)(p0 + wave * 16 + nh) * 12 + q * 4) = o;
    }
  }
}

// ---- launch ----------------------------------------------------------------
extern "C" void kernel_launch(void* const* d_in, const int* in_sizes, int n_in,
                              void* d_out, int out_size, void* d_ws, size_t ws_size,
                              hipStream_t stream) {
  const float* x      = (const float*)d_in[0];
  const int*   inds   = (const int*)d_in[1];
  const int*   invmap = (const int*)d_in[2];
  const int M = in_sizes[1];

  unsigned short* wt   = (unsigned short*)d_ws;
  unsigned short* vout = (unsigned short*)((char*)d_ws + (1 << 20));

  PrepArgs pa;
  pa.src[0]  = (const float*)d_in[3];
  pa.src[1]  = (const float*)d_in[5];
  pa.src[2]  = (const float*)d_in[7];
  pa.src[3]  = (const float*)d_in[9];
  pa.src[4]  = (const float*)d_in[11];
  pa.src[5]  = (const float*)d_in[13];
  pa.src[6]  = (const float*)d_in[15];
  pa.src[7]  = (const float*)d_in[17];
  pa.src[8]  = (const float*)d_in[19];
  pa.src[9]  = (const float*)d_in[21];
  pa.src[10] = (const float*)d_in[23];
  pa.src[11] = (const float*)d_in[25];

  float* outM = (float*)d_out + (size_t)N_PTS * 12;
  prep_k<<<(WT_TOTAL / 8 + 255) / 256, 256, 0, stream>>>(pa, wt, outM, (float)M);

  voxel_k<<<(M + 63) / 64, 256, 0, stream>>>(x, inds, wt,
                                             (const float*)d_in[8],
                                             (const float*)d_in[10],
                                             vout, M);

  MainArgs ma;
  ma.x = x; ma.invmap = invmap; ma.wt = wt; ma.vout = vout; ma.out = (float*)d_out;
  ma.fb1 = (const float*)d_in[4];  ma.fb2 = (const float*)d_in[6];
  ma.bb1 = (const float*)d_in[12]; ma.bb2 = (const float*)d_in[14]; ma.bb3 = (const float*)d_in[16];
  ma.nb0 = (const float*)d_in[18]; ma.nb2 = (const float*)d_in[20];
  ma.nb4 = (const float*)d_in[22]; ma.nb6 = (const float*)d_in[24]; ma.nb8 = (const float*)d_in[26];
  main_k<<<N_PTS / 64, 512, 0, stream>>>(ma);
}

// Round 9
// 372.210 us; speedup vs baseline: 1.0173x; 1.0117x over previous
//
#include <hip/hip_runtime.h>

#define N_PTS 262144
#define X_STRIDE 79

using floatx4   = __attribute__((ext_vector_type(4))) float;
using floatx4a  = __attribute__((ext_vector_type(4), aligned(4))) float;
using floatx16  = __attribute__((ext_vector_type(16))) float;
using half8     = __attribute__((ext_vector_type(8))) _Float16;
using ushort8v  = __attribute__((ext_vector_type(8))) unsigned short;
using uint2v    = __attribute__((ext_vector_type(2))) unsigned int;

__device__ __forceinline__ unsigned short f2h(float f) {
  _Float16 h = (_Float16)f;
  return __builtin_bit_cast(unsigned short, h);
}
__device__ __forceinline__ unsigned int pk2(float a, float b) {
  return __builtin_bit_cast(unsigned int, __builtin_amdgcn_cvt_pkrtz(a, b));
}
// XOR swizzle for reg2: 256-elem rows, 16B chunks rotated by row.
__device__ __forceinline__ int swz(int row, int col) {
  return row * 256 + (((col >> 3) ^ (row & 31)) << 3) + (col & 7);
}

// ---- weight table: FRAGMENT-MAJOR fp16 -------------------------------------
// layer:        fw1 fw2 uw1 uw2 bw1 bw2 bw3 nw0 nw2 nw4 nw6 nw8
__device__ const int T_KS[12]  = {63, 64, 63,128,128, 64, 64,140,256,396,256,256};
__device__ const int T_NS[12]  = {64, 64,128, 64, 64, 64, 64,256,256,256,256, 12};
__device__ const int T_KP[12]  = {64, 64, 64,128,128, 64, 64,144,256,400,256,256};
__device__ const int T_OFF[13] = {0,4096,8192,16384,24576,32768,36864,40960,
                                  77824,143360,245760,311296,315392};
#define OFF_FW1 0
#define OFF_FW2 4096
#define OFF_UW1 8192
#define OFF_UW2 16384
#define OFF_BW1 24576
#define OFF_BW2 32768
#define OFF_BW3 36864
#define OFF_NW0 40960
#define OFF_NW2 77824
#define OFF_NW4 143360
#define OFF_NW6 245760
#define OFF_NW8 311296
#define WT_TOTAL 315392

template<int NJ, int NM, int SWZ>
__device__ __forceinline__ void accum32(floatx16 (&acc)[NJ][NM],
    const unsigned short* ldsB, int strideB, int mrow0, int colB,
    const unsigned short* wtL, int KTtot, int jg0,
    int sBegin, int sEnd, int sBBase) {
  const int lane = threadIdx.x & 63;
  const int pr = lane & 31, h = lane >> 5;
#pragma unroll 4
  for (int s = sBegin; s < sEnd; ++s) {
    half8 b[NM];
#pragma unroll
    for (int m = 0; m < NM; ++m) {
      int row = mrow0 + m * 32 + pr;
      int col = colB + (s - sBBase) * 16 + h * 8;
      int off = SWZ ? swz(row, col) : (row * strideB + col);
      b[m] = *reinterpret_cast<const half8*>(ldsB + off);
    }
#pragma unroll
    for (int j = 0; j < NJ; ++j) {
      half8 w = *reinterpret_cast<const half8*>(
          wtL + (size_t)(((jg0 + j) * KTtot + s) * 64 + lane) * 8);
#pragma unroll
      for (int m = 0; m < NM; ++m)
        acc[j][m] = __builtin_amdgcn_mfma_f32_32x32x16_f16(w, b[m], acc[j][m], 0, 0, 0);
    }
  }
}

template<int NJ, int NM>
__device__ __forceinline__ void zero32(floatx16 (&acc)[NJ][NM]) {
#pragma unroll
  for (int j = 0; j < NJ; ++j)
#pragma unroll
    for (int m = 0; m < NM; ++m)
#pragma unroll
      for (int r = 0; r < 16; ++r) acc[j][m][r] = 0.f;
}

template<int NJ, int NM, int SWZ>
__device__ __forceinline__ void epi32(const floatx16 (&acc)[NJ][NM],
    unsigned short* ldsOut, int strideO, int colOff, int mrow0,
    const float* bias, int biasBase, bool relu) {
  const int lane = threadIdx.x & 63;
  const int pr = lane & 31, h = lane >> 5;
#pragma unroll
  for (int j = 0; j < NJ; ++j) {
#pragma unroll
    for (int g = 0; g < 4; ++g) {
      floatx4 b4 = *reinterpret_cast<const floatx4*>(bias + biasBase + j * 32 + g * 8 + h * 4);
#pragma unroll
      for (int m = 0; m < NM; ++m) {
        float v0 = acc[j][m][g * 4 + 0] + b4[0];
        float v1 = acc[j][m][g * 4 + 1] + b4[1];
        float v2 = acc[j][m][g * 4 + 2] + b4[2];
        float v3 = acc[j][m][g * 4 + 3] + b4[3];
        if (relu) {
          v0 = fmaxf(v0, 0.f); v1 = fmaxf(v1, 0.f);
          v2 = fmaxf(v2, 0.f); v3 = fmaxf(v3, 0.f);
        }
        uint2v hv; hv[0] = pk2(v0, v1); hv[1] = pk2(v2, v3);
        int row = mrow0 + m * 32 + pr;
        int col = colOff + j * 32 + g * 8 + h * 4;
        int off = SWZ ? swz(row, col) : (row * strideO + col);
        *reinterpret_cast<uint2v*>(ldsOut + off) = hv;
      }
    }
  }
}

template<int NJ, int KT, int SWZ>
__device__ __forceinline__ void accum16nj(floatx4 (&acc)[NJ],
    const unsigned short* ldsB, int strideB, int mrow0, int colB,
    const unsigned short* wtL, int jg0) {
  const int lane = threadIdx.x & 63;
  const int nh = lane & 15, q = lane >> 4;
#pragma unroll
  for (int s = 0; s < KT; ++s) {
    int row = mrow0 + nh;
    int col = colB + s * 32 + q * 8;
    int off = SWZ ? swz(row, col) : (row * strideB + col);
    half8 b = *reinterpret_cast<const half8*>(ldsB + off);
#pragma unroll
    for (int j = 0; j < NJ; ++j) {
      half8 w = *reinterpret_cast<const half8*>(
          wtL + (size_t)(((jg0 + j) * KT + s) * 64 + lane) * 8);
      acc[j] = __builtin_amdgcn_mfma_f32_16x16x32_f16(w, b, acc[j], 0, 0, 0);
    }
  }
}

template<int NJ, int SWZ>
__device__ __forceinline__ void epi16nj(const floatx4 (&acc)[NJ],
    unsigned short* ldsOut, int strideO, int colOff, int mrow0,
    const float* bias, int biasBase, bool relu) {
  const int lane = threadIdx.x & 63;
  const int nh = lane & 15, q = lane >> 4;
#pragma unroll
  for (int j = 0; j < NJ; ++j) {
    floatx4 b4 = *reinterpret_cast<const floatx4*>(bias + biasBase + j * 16 + q * 4);
    float v0 = acc[j][0] + b4[0];
    float v1 = acc[j][1] + b4[1];
    float v2 = acc[j][2] + b4[2];
    float v3 = acc[j][3] + b4[3];
    if (relu) {
      v0 = fmaxf(v0, 0.f); v1 = fmaxf(v1, 0.f);
      v2 = fmaxf(v2, 0.f); v3 = fmaxf(v3, 0.f);
    }
    uint2v hv; hv[0] = pk2(v0, v1); hv[1] = pk2(v2, v3);
    int row = mrow0 + nh;
    int col = colOff + j * 16 + q * 4;
    int off = SWZ ? swz(row, col) : (row * strideO + col);
    *reinterpret_cast<uint2v*>(ldsOut + off) = hv;
  }
}

// ---- kernel 1: weight repack + scalar output -------------------------------
struct PrepArgs { const float* src[12]; };

__global__ __launch_bounds__(256) void prep_k(PrepArgs a, unsigned short* wt,
                                              float* outM, float Mval) {
  int chunk = blockIdx.x * 256 + threadIdx.x;
  if (chunk == 0) *outM = Mval;
  if (chunk >= WT_TOTAL / 8) return;
  int gid = chunk * 8;
  int L = 0;
  while (gid >= T_OFF[L + 1]) ++L;
  int local = chunk - T_OFF[L] / 8;
  int lane = local & 63;
  int t = local >> 6;
  bool is16 = (L < 2) || (L >= 4 && L <= 6) || (L == 11);
  int n, k0;
  if (is16) {
    int KT = T_KP[L] >> 5;
    int s = t % KT, j = t / KT;
    n = j * 16 + (lane & 15);
    k0 = s * 32 + (lane >> 4) * 8;
  } else {
    int KT = T_KP[L] >> 4;
    int s = t % KT, j = t / KT;
    n = j * 32 + (lane & 31);
    k0 = s * 16 + (lane >> 5) * 8;
  }
  const float* src = a.src[L];
  int K = T_KS[L], Nn = T_NS[L];
  ushort8v o;
#pragma unroll
  for (int i = 0; i < 8; ++i) {
    int k = k0 + i;
    float v = (k < K && n < Nn) ? src[(size_t)k * Nn + n] : 0.f;
    o[i] = f2h(v);
  }
  *reinterpret_cast<ushort8v*>(wt + gid) = o;
}

// ---- kernel 2: voxel branch (round-6 structure) ----------------------------
__global__ __launch_bounds__(256, 3) void voxel_k(const float* __restrict__ x,
                                                  const int* __restrict__ inds,
                                                  const unsigned short* __restrict__ wt,
                                                  const float* __restrict__ ub1,
                                                  const float* __restrict__ ub2,
                                                  unsigned short* __restrict__ vout, int M) {
  __shared__ unsigned short bufV[64 * 72];
  __shared__ unsigned short bufU[64 * 136];
  const int wave = threadIdx.x >> 6, lane = threadIdx.x & 63;
  const int pr = lane & 31, h = lane >> 5;
  const int v0 = blockIdx.x * 64;

  for (int idx = threadIdx.x; idx < 64 * 16; idx += 256) {
    int p = idx >> 4, g = idx & 15;
    int v = v0 + p;
    uint2v hv; hv[0] = 0u; hv[1] = 0u;
    if (v < M) {
      floatx4a f = *reinterpret_cast<const floatx4a*>(
          x + (size_t)inds[v] * X_STRIDE + g * 4);
      if (g == 15) f[3] = 0.f;
      hv[0] = pk2(f[0], f[1]); hv[1] = pk2(f[2], f[3]);
    }
    *reinterpret_cast<uint2v*>(bufV + p * 72 + g * 4) = hv;
  }
  __syncthreads();

  {
    floatx16 acc[2][1];
    zero32<2, 1>(acc);
    int jg0 = (wave & 1) * 2, m0 = (wave >> 1) * 32;
    accum32<2, 1, 0>(acc, bufV, 72, m0, 0, wt + OFF_UW1, 4, jg0, 0, 4, 0);
    epi32<2, 1, 0>(acc, bufU, 136, jg0 * 32, m0, ub1, jg0 * 32, true);
  }
  __syncthreads();

  {
    floatx16 acc[1][1];
    zero32<1, 1>(acc);
    int j = wave & 1, m0 = (wave >> 1) * 32;
    accum32<1, 1, 0>(acc, bufU, 136, m0, 0, wt + OFF_UW2, 8, j, 0, 8, 0);
    int v = v0 + m0 + pr;
    if (v < M) {
#pragma unroll
      for (int g = 0; g < 4; ++g) {
        floatx4 b4 = *reinterpret_cast<const floatx4*>(ub2 + j * 32 + g * 8 + h * 4);
        uint2v hv;
        hv[0] = pk2(acc[0][0][g * 4 + 0] + b4[0], acc[0][0][g * 4 + 1] + b4[1]);
        hv[1] = pk2(acc[0][0][g * 4 + 2] + b4[2], acc[0][0][g * 4 + 3] + b4[3]);
        *reinterpret_cast<uint2v*>(vout + (size_t)v * 64 + j * 32 + g * 8 + h * 4) = hv;
      }
    }
  }
}

// ---- kernel 3: fused pipeline, 64 pts/block, 8 waves, swizzled reg2 --------
// launch_bounds(512, 4): VGPR cap 128 -> NO accumulator spill (round-8 lesson:
// (512,6) capped at ~85 and spilled acc to scratch: WRITE_SIZE 12->68 MB).
struct MainArgs {
  const float* x;
  const int* invmap;
  const unsigned short* wt;
  const unsigned short* vout;
  float* out;
  const float* fb1; const float* fb2;
  const float* bb1; const float* bb2; const float* bb3;
  const float* nb0; const float* nb2; const float* nb4; const float* nb6; const float* nb8;
};

__global__ __launch_bounds__(512, 4) void main_k(MainArgs a) {
  __shared__ unsigned short bufX[64 * 152];   // linear: x[0,76)|back[76,140)|0
  __shared__ unsigned short reg2[64 * 256];   // swizzled
  const int wave = threadIdx.x >> 6, lane = threadIdx.x & 63;
  const int p0 = blockIdx.x * 64;

  for (int idx = threadIdx.x; idx < 64 * 19; idx += 512) {
    int p = idx / 19, g = idx - p * 19;
    floatx4a f = *reinterpret_cast<const floatx4a*>(
        a.x + (size_t)(p0 + p) * X_STRIDE + g * 4);
    uint2v hv; hv[0] = pk2(f[0], f[1]); hv[1] = pk2(f[2], f[3]);
    *reinterpret_cast<uint2v*>(bufX + p * 152 + g * 4) = hv;
  }
  for (int idx = threadIdx.x; idx < 64 * 3; idx += 512) {
    int p = idx / 3, c = (idx - p * 3) * 4;
    uint2v z; z[0] = 0u; z[1] = 0u;
    *reinterpret_cast<uint2v*>(bufX + p * 152 + 140 + c) = z;
  }
  {
    int p = threadIdx.x >> 3, cc = threadIdx.x & 7;
    int r = a.invmap[p0 + p];
    *reinterpret_cast<ushort8v*>(reg2 + p * 256 + (((8 + cc) ^ (p & 31)) << 3)) =
        *reinterpret_cast<const ushort8v*>(a.vout + (size_t)r * 64 + cc * 8);
  }
  __syncthreads();

  // ---- chain: 16x16x32, all 8 waves (m16 = 16 pts, jg2 = 2 j-tiles) ----
  const int m16 = (wave >> 1) * 16;
  const int jg2 = (wave & 1) * 2;
  {
    floatx4 acc[2];
    acc[0] = floatx4{0.f,0.f,0.f,0.f}; acc[1] = floatx4{0.f,0.f,0.f,0.f};
    accum16nj<2, 2, 0>(acc, bufX, 152, m16, 0, a.wt + OFF_FW1, jg2);
    epi16nj<2, 1>(acc, reg2, 0, 128 + jg2 * 16, m16, a.fb1, jg2 * 16, true);
    __syncthreads();
    acc[0] = floatx4{0.f,0.f,0.f,0.f}; acc[1] = floatx4{0.f,0.f,0.f,0.f};
    accum16nj<2, 2, 1>(acc, reg2, 0, m16, 128, a.wt + OFF_FW2, jg2);
    epi16nj<2, 1>(acc, reg2, 0, 0 + jg2 * 16, m16, a.fb2, jg2 * 16, false);
    __syncthreads();
    acc[0] = floatx4{0.f,0.f,0.f,0.f}; acc[1] = floatx4{0.f,0.f,0.f,0.f};
    accum16nj<2, 4, 1>(acc, reg2, 0, m16, 0, a.wt + OFF_BW1, jg2);
    epi16nj<2, 1>(acc, reg2, 0, 128 + jg2 * 16, m16, a.bb1, jg2 * 16, true);
    __syncthreads();
    acc[0] = floatx4{0.f,0.f,0.f,0.f}; acc[1] = floatx4{0.f,0.f,0.f,0.f};
    accum16nj<2, 2, 1>(acc, reg2, 0, m16, 128, a.wt + OFF_BW2, jg2);
    epi16nj<2, 1>(acc, reg2, 0, 192 + jg2 * 16, m16, a.bb2, jg2 * 16, true);
    __syncthreads();
    acc[0] = floatx4{0.f,0.f,0.f,0.f}; acc[1] = floatx4{0.f,0.f,0.f,0.f};
    accum16nj<2, 2, 1>(acc, reg2, 0, m16, 192, a.wt + OFF_BW3, jg2);
    epi16nj<2, 0>(acc, bufX, 152, 76 + jg2 * 16, m16, a.bb3, jg2 * 16, false);
    __syncthreads();
  }

  // ---- 256-wide layers: NJ=1 (32 feats/wave), NM=2 (64 pts) ----
  {
    floatx16 acc[1][2];
    zero32<1, 2>(acc);
    accum32<1, 2, 0>(acc, bufX, 152, 0, 0, a.wt + OFF_NW0, 9, wave, 0, 9, 0);
    epi32<1, 2, 1>(acc, reg2, 0, wave * 32, 0, a.nb0, wave * 32, true);
  }
  __syncthreads();
  {
    floatx16 acc[1][2];
    zero32<1, 2>(acc);
    accum32<1, 2, 1>(acc, reg2, 0, 0, 0, a.wt + OFF_NW2, 16, wave, 0, 16, 0);
    __syncthreads();
    epi32<1, 2, 1>(acc, reg2, 0, wave * 32, 0, a.nb2, wave * 32, true);
  }
  __syncthreads();
  {
    floatx16 acc[1][2];
    zero32<1, 2>(acc);
    accum32<1, 2, 1>(acc, reg2, 0, 0, 0, a.wt + OFF_NW4, 25, wave, 0, 16, 0);
    accum32<1, 2, 0>(acc, bufX, 152, 0, 0, a.wt + OFF_NW4, 25, wave, 16, 25, 16);
    __syncthreads();
    epi32<1, 2, 1>(acc, reg2, 0, wave * 32, 0, a.nb4, wave * 32, true);
  }
  __syncthreads();
  {
    floatx16 acc[1][2];
    zero32<1, 2>(acc);
    accum32<1, 2, 1>(acc, reg2, 0, 0, 0, a.wt + OFF_NW6, 16, wave, 0, 16, 0);
    __syncthreads();
    epi32<1, 2, 1>(acc, reg2, 0, wave * 32, 0, a.nb6, wave * 32, true);
  }
  __syncthreads();
  if (wave < 4) {
    const int nh = lane & 15, q = lane >> 4;
    floatx4 acc[1];
    acc[0] = floatx4{0.f, 0.f, 0.f, 0.f};
    accum16nj<1, 8, 1>(acc, reg2, 0, wave * 16, 0, a.wt + OFF_NW8, 0);
    if (q < 3) {
      floatx4 o;
#pragma unroll
      for (int r = 0; r < 4; ++r) o[r] = acc[0][r] + a.nb8[q * 4 + r];
      *reinterpret_cast<floatx4*>(a.out + (size_t)(p0 + wave * 16 + nh) * 12 + q * 4) = o;
    }
  }
}

// ---- launch ----------------------------------------------------------------
extern "C" void kernel_launch(void* const* d_in, const int* in_sizes, int n_in,
                              void* d_out, int out_size, void* d_ws, size_t ws_size,
                              hipStream_t stream) {
  const float* x      = (const float*)d_in[0];
  const int*   inds   = (const int*)d_in[1];
  const int*   invmap = (const int*)d_in[2];
  const int M = in_sizes[1];

  unsigned short* wt   = (unsigned short*)d_ws;
  unsigned short* vout = (unsigned short*)((char*)d_ws + (1 << 20));

  PrepArgs pa;
  pa.src[0]  = (const float*)d_in[3];
  pa.src[1]  = (const float*)d_in[5];
  pa.src[2]  = (const float*)d_in[7];
  pa.src[3]  = (const float*)d_in[9];
  pa.src[4]  = (const float*)d_in[11];
  pa.src[5]  = (const float*)d_in[13];
  pa.src[6]  = (const float*)d_in[15];
  pa.src[7]  = (const float*)d_in[17];
  pa.src[8]  = (const float*)d_in[19];
  pa.src[9]  = (const float*)d_in[21];
  pa.src[10] = (const float*)d_in[23];
  pa.src[11] = (const float*)d_in[25];

  float* outM = (float*)d_out + (size_t)N_PTS * 12;
  prep_k<<<(WT_TOTAL / 8 + 255) / 256, 256, 0, stream>>>(pa, wt, outM, (float)M);

  voxel_k<<<(M + 63) / 64, 256, 0, stream>>>(x, inds, wt,
                                             (const float*)d_in[8],
                                             (const float*)d_in[10],
                                             vout, M);

  MainArgs ma;
  ma.x = x; ma.invmap = invmap; ma.wt = wt; ma.vout = vout; ma.out = (float*)d_out;
  ma.fb1 = (const float*)d_in[4];  ma.fb2 = (const float*)d_in[6];
  ma.bb1 = (const float*)d_in[12]; ma.bb2 = (const float*)d_in[14]; ma.bb3 = (const float*)d_in[16];
  ma.nb0 = (const float*)d_in[18]; ma.nb2 = (const float*)d_in[20];
  ma.nb4 = (const float*)d_in[22]; ma.nb6 = (const float*)d_in[24]; ma.nb8 = (const float*)d_in[26];
  main_k<<<N_PTS / 64, 512, 0, stream>>>(ma);
}